// Round 2
// baseline (198.197 us; speedup 1.0000x reference)
//
#include <hip/hip_runtime.h>
#include <math.h>

// Problem constants (from reference setup_inputs): bases [1,4,136,200] f32,
// box_feat [N,789] f32 (col0 = image idx, 1:5 = box, 5: = 4*14*14 coeffs),
// output [N,544,800] f32.
#define OUTD 56
#define COD  14
#define BH   136
#define BW   200
#define IMGH 544
#define IMGW 800
#define BB   4
#define BFS  789   // 5 + 4*14*14

// ---------------------------------------------------------------------------
// Fully fused: one block per (roi, image-row). Block computes the <=2 mask
// rows (2x56 values) this image row bilinearly samples, into LDS, then each
// thread writes one float4 of the output row (coalesced). Mask values are
// recomputed ~10x across image rows but that's ~6M cheap cache-hot evals.
// Mask value = sigmoid( sum_b roi_align(bases_b) * softmax_b(upsample(coeff)) ).
// ---------------------------------------------------------------------------

__device__ __forceinline__ float mask_value(
    const float* __restrict__ feat,   // bases + bidx*BB*BH*BW
    const float* __restrict__ top,    // bf + 5
    float sx0, float sy0, float bw, float bh,
    int y, int x) {
  // ---- roi_align sample (aligned=True, sampling_ratio=1) ----
  const float ysv = sy0 + ((float)y + 0.5f) * bh;
  const float xsv = sx0 + ((float)x + 0.5f) * bw;
  const float valid =
      (ysv >= -1.0f && ysv <= (float)BH && xsv >= -1.0f && xsv <= (float)BW)
          ? 1.0f : 0.0f;
  const float yc = fminf(fmaxf(ysv, 0.0f), (float)(BH - 1));
  const float xc = fminf(fmaxf(xsv, 0.0f), (float)(BW - 1));
  int yl = (int)floorf(yc); yl = yl > (BH - 2) ? (BH - 2) : yl;  // yc >= 0
  int xl = (int)floorf(xc); xl = xl > (BW - 2) ? (BW - 2) : xl;
  const float ly = yc - (float)yl, hy = 1.0f - ly;
  const float lx = xc - (float)xl, hx = 1.0f - lx;
  const float w00 = hy * hx, w01 = hy * lx, w10 = ly * hx, w11 = ly * lx;

  // ---- coeff 14->56 bilinear upsample coords (edge clamp) ----
  float cyf = fminf(fmaxf(((float)y + 0.5f) * 0.25f - 0.5f, 0.0f), (float)(COD - 1));
  float cxf = fminf(fmaxf(((float)x + 0.5f) * 0.25f - 0.5f, 0.0f), (float)(COD - 1));
  int cyl = (int)floorf(cyf); cyl = cyl > (COD - 2) ? (COD - 2) : cyl;
  int cxl = (int)floorf(cxf); cxl = cxl > (COD - 2) ? (COD - 2) : cxl;
  const float cly = cyf - (float)cyl, chy = 1.0f - cly;
  const float clx = cxf - (float)cxl, chx = 1.0f - clx;
  const float cw00 = chy * chx, cw01 = chy * clx, cw10 = cly * chx, cw11 = cly * clx;

  float rvals[BB], cvals[BB];
#pragma unroll
  for (int b = 0; b < BB; ++b) {
    const float* fb = feat + b * BH * BW;
    const float r = w00 * fb[yl * BW + xl]       + w01 * fb[yl * BW + xl + 1] +
                    w10 * fb[(yl + 1) * BW + xl] + w11 * fb[(yl + 1) * BW + xl + 1];
    rvals[b] = r * valid;
    const float* tb = top + b * COD * COD;
    cvals[b] = cw00 * tb[cyl * COD + cxl]       + cw01 * tb[cyl * COD + cxl + 1] +
               cw10 * tb[(cyl + 1) * COD + cxl] + cw11 * tb[(cyl + 1) * COD + cxl + 1];
  }

  const float mx = fmaxf(fmaxf(cvals[0], cvals[1]), fmaxf(cvals[2], cvals[3]));
  float e[BB], s = 0.0f;
#pragma unroll
  for (int b = 0; b < BB; ++b) { e[b] = __expf(cvals[b] - mx); s += e[b]; }
  const float inv = 1.0f / s;
  float dot = 0.0f;
#pragma unroll
  for (int b = 0; b < BB; ++b) dot += rvals[b] * (e[b] * inv);
  return 1.0f / (1.0f + __expf(-dot));
}

__global__ __launch_bounds__(256) void fused_blend_paste(
    const float* __restrict__ bases,
    const float* __restrict__ box_feat,
    float4* __restrict__ out) {
  const int h = blockIdx.x;   // image row
  const int n = blockIdx.y;   // roi
  const int tid = threadIdx.x;

  const float* bf = box_feat + (size_t)n * BFS;
  const float x0 = bf[1], y0 = bf[2], x1 = bf[3], y1 = bf[4];

  float4* orow = out + ((size_t)n * IMGH + h) * (IMGW / 4);
  const float fy = ((float)h + 0.5f - y0) * ((float)OUTD / (y1 - y0)) - 0.5f;

  // Whole row outside the box's vertical tent support -> zero row (uniform).
  if (!(fy > -1.0f && fy < (float)OUTD)) {
    if (tid < IMGW / 4) orow[tid] = make_float4(0.f, 0.f, 0.f, 0.f);
    return;
  }

  const int ml = (int)floorf(fy);      // may be -1..55
  const float wy1 = fy - (float)ml;
  const float wy0 = 1.0f - wy1;

  __shared__ float mrow[2][OUTD];

  if (tid < 2 * OUTD) {
    const int r_idx = (tid >= OUTD) ? 1 : 0;
    const int x = tid - r_idx * OUTD;
    const int r = ml + r_idx;
    float val = 0.0f;
    if (r >= 0 && r < OUTD) {
      const int bidx = (int)bf[0];
      const float sx0 = x0 * 0.25f - 0.5f;
      const float sy0 = y0 * 0.25f - 0.5f;
      const float bwv = (x1 - x0) * 0.25f * (1.0f / OUTD);
      const float bhv = (y1 - y0) * 0.25f * (1.0f / OUTD);
      const float* feat = bases + (size_t)bidx * BB * BH * BW;
      val = mask_value(feat, bf + 5, sx0, sy0, bwv, bhv, r, x);
    }
    mrow[r_idx][x] = val;    // zero for invalid rows => zero-pad semantics
  }
  __syncthreads();

  if (tid >= IMGW / 4) return;

  const float invw = (float)OUTD / (x1 - x0);
  float res[4];
#pragma unroll
  for (int i = 0; i < 4; ++i) {
    const int q = tid * 4 + i;
    const float fx = ((float)q + 0.5f - x0) * invw - 0.5f;
    float v = 0.0f;
    if (fx > -1.0f && fx < (float)OUTD) {
      const int xl = (int)floorf(fx);
      const float wx1 = fx - (float)xl;
      const float wx0 = 1.0f - wx1;
      const bool xlv = (xl >= 0);
      const bool xhv = (xl + 1 <= OUTD - 1);
      const int xls = xlv ? xl : 0;
      const int xhs = xhv ? (xl + 1) : 0;
      const float v00 = xlv ? mrow[0][xls] : 0.0f;
      const float v01 = xhv ? mrow[0][xhs] : 0.0f;
      const float v10 = xlv ? mrow[1][xls] : 0.0f;
      const float v11 = xhv ? mrow[1][xhs] : 0.0f;
      v = wy0 * (wx0 * v00 + wx1 * v01) + wy1 * (wx0 * v10 + wx1 * v11);
    }
    res[i] = v;
  }
  orow[tid] = make_float4(res[0], res[1], res[2], res[3]);
}

extern "C" void kernel_launch(void* const* d_in, const int* in_sizes, int n_in,
                              void* d_out, int out_size, void* d_ws, size_t ws_size,
                              hipStream_t stream) {
  const float* bases    = (const float*)d_in[0];
  const float* box_feat = (const float*)d_in[1];
  const int N = in_sizes[1] / BFS;

  dim3 grid(IMGH, N);
  fused_blend_paste<<<grid, 256, 0, stream>>>(bases, box_feat, (float4*)d_out);
}

// Round 3
// 175.013 us; speedup vs baseline: 1.1325x; 1.1325x over previous
//
#include <hip/hip_runtime.h>
#include <math.h>

// Problem constants: bases [1,4,136,200] f32, box_feat [N,789] f32
// (col0 = image idx, 1:5 = box, 5: = 4*14*14 coeffs), out [N,544,800] f32.
#define OUTD 56
#define COD  14
#define BH   136
#define BW   200
#define IMGH 544
#define IMGW 800
#define BB   4
#define BFS  789   // 5 + 4*14*14

// ---------------------------------------------------------------------------
// K1: build N 56x56 sigmoid masks into workspace. ONE THREAD PER PIXEL
// (grid = 13 x N) so the whole chip participates and no thread serializes
// multiple latency-chained heavy evals (R1 used 100 blocks = 100 CUs, 13
// serial evals/thread).
// ---------------------------------------------------------------------------
__global__ __launch_bounds__(256) void mask_kernel(
    const float* __restrict__ bases,
    const float* __restrict__ box_feat,
    float* __restrict__ masks) {
  const int n = blockIdx.y;
  const int p = blockIdx.x * 256 + threadIdx.x;
  if (p >= OUTD * OUTD) return;
  const int y = p / OUTD;
  const int x = p - y * OUTD;

  const float* bf = box_feat + (size_t)n * BFS;
  const int bidx = (int)bf[0];
  const float x0 = bf[1], y0 = bf[2], x1 = bf[3], y1 = bf[4];
  const float sx0 = x0 * 0.25f - 0.5f;
  const float sy0 = y0 * 0.25f - 0.5f;
  const float bwv = (x1 - x0) * 0.25f * (1.0f / OUTD);
  const float bhv = (y1 - y0) * 0.25f * (1.0f / OUTD);
  const float* feat = bases + (size_t)bidx * BB * BH * BW;
  const float* top  = bf + 5;

  // ---- roi_align sample (aligned=True, sampling_ratio=1) ----
  const float ysv = sy0 + ((float)y + 0.5f) * bhv;
  const float xsv = sx0 + ((float)x + 0.5f) * bwv;
  const float valid =
      (ysv >= -1.0f && ysv <= (float)BH && xsv >= -1.0f && xsv <= (float)BW)
          ? 1.0f : 0.0f;
  const float yc = fminf(fmaxf(ysv, 0.0f), (float)(BH - 1));
  const float xc = fminf(fmaxf(xsv, 0.0f), (float)(BW - 1));
  int yl = (int)floorf(yc); yl = yl > (BH - 2) ? (BH - 2) : yl;  // yc >= 0
  int xl = (int)floorf(xc); xl = xl > (BW - 2) ? (BW - 2) : xl;
  const float ly = yc - (float)yl, hy = 1.0f - ly;
  const float lx = xc - (float)xl, hx = 1.0f - lx;
  const float w00 = hy * hx, w01 = hy * lx, w10 = ly * hx, w11 = ly * lx;

  // ---- coeff 14->56 bilinear upsample coords (edge clamp) ----
  float cyf = fminf(fmaxf(((float)y + 0.5f) * 0.25f - 0.5f, 0.0f), (float)(COD - 1));
  float cxf = fminf(fmaxf(((float)x + 0.5f) * 0.25f - 0.5f, 0.0f), (float)(COD - 1));
  int cyl = (int)floorf(cyf); cyl = cyl > (COD - 2) ? (COD - 2) : cyl;
  int cxl = (int)floorf(cxf); cxl = cxl > (COD - 2) ? (COD - 2) : cxl;
  const float cly = cyf - (float)cyl, chy = 1.0f - cly;
  const float clx = cxf - (float)cxl, chx = 1.0f - clx;
  const float cw00 = chy * chx, cw01 = chy * clx, cw10 = cly * chx, cw11 = cly * clx;

  float rvals[BB], cvals[BB];
#pragma unroll
  for (int b = 0; b < BB; ++b) {
    const float* fb = feat + b * BH * BW;
    const float r = w00 * fb[yl * BW + xl]       + w01 * fb[yl * BW + xl + 1] +
                    w10 * fb[(yl + 1) * BW + xl] + w11 * fb[(yl + 1) * BW + xl + 1];
    rvals[b] = r * valid;
    const float* tb = top + b * COD * COD;
    cvals[b] = cw00 * tb[cyl * COD + cxl]       + cw01 * tb[cyl * COD + cxl + 1] +
               cw10 * tb[(cyl + 1) * COD + cxl] + cw11 * tb[(cyl + 1) * COD + cxl + 1];
  }

  const float mx = fmaxf(fmaxf(cvals[0], cvals[1]), fmaxf(cvals[2], cvals[3]));
  float e[BB], s = 0.0f;
#pragma unroll
  for (int b = 0; b < BB; ++b) { e[b] = __expf(cvals[b] - mx); s += e[b]; }
  const float inv = 1.0f / s;
  float dot = 0.0f;
#pragma unroll
  for (int b = 0; b < BB; ++b) dot += rvals[b] * (e[b] * inv);
  masks[(size_t)n * (OUTD * OUTD) + p] = 1.0f / (1.0f + __expf(-dot));
}

// ---------------------------------------------------------------------------
// K2: paste. One block per (image-row, roi): no integer divides, box/fy are
// block-uniform (scalar regs), zero rows take a uniform 1-store fast path,
// valid rows stage the 2 needed mask rows (contiguous in memory) into LDS.
// Each of 200 threads writes one coalesced float4.
// ---------------------------------------------------------------------------
__global__ __launch_bounds__(256) void paste_kernel(
    const float* __restrict__ masks,
    const float* __restrict__ box_feat,
    float4* __restrict__ out) {
  const int h = blockIdx.x;
  const int n = blockIdx.y;
  const int tid = threadIdx.x;

  const float* bf = box_feat + (size_t)n * BFS;
  const float y0 = bf[2], y1 = bf[4];
  float4* orow = out + ((size_t)n * IMGH + h) * (IMGW / 4);

  const float fy = ((float)h + 0.5f - y0) * ((float)OUTD / (y1 - y0)) - 0.5f;

  if (!(fy > -1.0f && fy < (float)OUTD)) {         // block-uniform
    if (tid < IMGW / 4) orow[tid] = make_float4(0.f, 0.f, 0.f, 0.f);
    return;
  }

  const int ml = (int)floorf(fy);                   // -1 .. 55
  const float wy1 = fy - (float)ml;
  const float wy0 = 1.0f - wy1;

  __shared__ float mrow[2][OUTD];
  if (tid < 2 * OUTD) {
    const int r_idx = (tid >= OUTD) ? 1 : 0;
    const int x = tid - r_idx * OUTD;
    const int r = ml + r_idx;
    float v = 0.0f;
    if (r >= 0 && r < OUTD)
      v = masks[(size_t)n * (OUTD * OUTD) + r * OUTD + x];
    mrow[r_idx][x] = v;                             // 0 => zero-pad semantics
  }
  __syncthreads();

  if (tid >= IMGW / 4) return;

  const float x0 = bf[1], x1 = bf[3];
  const float invw = (float)OUTD / (x1 - x0);
  const float cx = (0.5f - x0) * invw - 0.5f;       // fx(q) = q*invw + cx

  float res[4];
#pragma unroll
  for (int i = 0; i < 4; ++i) {
    const float q = (float)(tid * 4 + i);
    const float fx = fmaf(q, invw, cx);
    float v = 0.0f;
    if (fx > -1.0f && fx < (float)OUTD) {
      const int xl = (int)floorf(fx);
      float wx1 = fx - (float)xl;
      float wx0 = 1.0f - wx1;
      const int xls = xl < 0 ? 0 : xl;
      const int xhs = (xl + 1 > OUTD - 1) ? (OUTD - 1) : (xl + 1);
      if (xl < 0) wx0 = 0.0f;
      if (xl + 1 > OUTD - 1) wx1 = 0.0f;
      v = wy0 * (wx0 * mrow[0][xls] + wx1 * mrow[0][xhs]) +
          wy1 * (wx0 * mrow[1][xls] + wx1 * mrow[1][xhs]);
    }
    res[i] = v;
  }
  orow[tid] = make_float4(res[0], res[1], res[2], res[3]);
}

extern "C" void kernel_launch(void* const* d_in, const int* in_sizes, int n_in,
                              void* d_out, int out_size, void* d_ws, size_t ws_size,
                              hipStream_t stream) {
  const float* bases    = (const float*)d_in[0];
  const float* box_feat = (const float*)d_in[1];
  const int N = in_sizes[1] / BFS;

  float* masks = (float*)d_ws;  // N*56*56 floats = 1.25 MB for N=100

  dim3 g1((OUTD * OUTD + 255) / 256, N);
  mask_kernel<<<g1, 256, 0, stream>>>(bases, box_feat, masks);

  dim3 g2(IMGH, N);
  paste_kernel<<<g2, 256, 0, stream>>>(masks, box_feat, (float4*)d_out);
}